// Round 10
// baseline (151.848 us; speedup 1.0000x reference)
//
#include <hip/hip_runtime.h>
#include <math.h>

#define KCODES 512
#define CDIM   64
#define HWPIX  4096
#define NPIX   131072
#define BLKPX  256
#define NBLK   (NPIX / BLKPX)   // 512
#define COMMIT 0.25f
#define TAU    0.0625f
#define CB_OFF 8192             // byte offset of codebook frag image in ws

typedef __attribute__((ext_vector_type(8))) short s16x8;   // 8 bf16
typedef __attribute__((ext_vector_type(4))) float f32x4;
typedef __attribute__((ext_vector_type(4))) unsigned u32x4;

static __device__ __forceinline__ unsigned umin_(unsigned a, unsigned b) { return a < b ? a : b; }
static __device__ __forceinline__ unsigned umax_(unsigned a, unsigned b) { return a > b ? a : b; }

static __device__ __forceinline__ unsigned short f2bf(float f) {   // RNE
    unsigned u = __float_as_uint(f);
    u += ((u >> 16) & 1u) + 0x7fffu;
    return (unsigned short)(u >> 16);
}
static __device__ __forceinline__ float bf2f(unsigned short h) {
    return __uint_as_float(((unsigned)h) << 16);
}
static __device__ __forceinline__ unsigned cvt_pk_bf16(float a, float b) {
    unsigned r;   // low half = bf16(a), high half = bf16(b), RNE
    asm("v_cvt_pk_bf16_f32 %0, %1, %2" : "=v"(r) : "v"(a), "v"(b));
    return r;
}

// ws (floats): [0..511] e2 | [512..1023] counts | [1024..1535] blockloss[512]
// byte 8192+: codebook frag image, 32 tiles x 4096B (tile = 16 codes).
// tile: hi frags at ks*1024, lo at 2048+ks*1024; 16B unit (lg*16+row)*16 holds
// code `row`, channels ks*32+lg*8..+7  -> wave A-frag read = base + lane*16.
__global__ void vq_prep(const float* __restrict__ emb, float* __restrict__ ws) {
    int k = blockIdx.x * 256 + threadIdx.x;   // 2 blocks x 256
    const float* e = emb + k * CDIM;
    float v[CDIM];
    double s = 0.0;
#pragma unroll
    for (int c = 0; c < CDIM; ++c) { v[c] = e[c]; s += (double)v[c] * (double)v[c]; }
    ws[k] = (float)s;
    ((unsigned*)ws)[KCODES + k] = 0u;

    unsigned char* base = (unsigned char*)ws + CB_OFF + (k >> 4) * 4096;
    const int row = k & 15;
#pragma unroll
    for (int ks = 0; ks < 2; ++ks) {
#pragma unroll
        for (int lg = 0; lg < 4; ++lg) {
            s16x8 hh, ll;
#pragma unroll
            for (int i = 0; i < 8; ++i) {
                float f = v[ks * 32 + lg * 8 + i];
                unsigned short hb = f2bf(f);
                hh[i] = (short)hb;
                ll[i] = (short)f2bf(f - bf2f(hb));
            }
            int off = (lg * 16 + row) * 16;
            *(s16x8*)(base + ks * 1024 + off)        = hh;
            *(s16x8*)(base + 2048 + ks * 1024 + off) = ll;
        }
    }
}

__global__ __launch_bounds__(256, 2)
void vq_main(const float* __restrict__ in, const float* __restrict__ emb,
             float* __restrict__ ws, float* __restrict__ out) {
    __shared__ __align__(16) unsigned char dbuf[2][32768];   // 128-code chunks
    __shared__ float  e2s[KCODES];
    __shared__ int    ls_idx[BLKPX];
    __shared__ float  ls_loss[BLKPX];
    __shared__ int    wl[BLKPX];
    __shared__ int    wlc;
    __shared__ float  wsum[4];
    __shared__ double rbd[4];
    __shared__ int    rbi[4];

    const int tid  = threadIdx.x;
    const int lane = tid & 63;
    const int wv   = tid >> 6;    // wave id: 64 px each
    const int lg   = lane >> 4;
    const int li   = lane & 15;
    const int blk  = blockIdx.x;
    const int n0   = blk * BLKPX;
    const int hw0  = n0 & 4095;
    const float* xb = in + (size_t)(n0 >> 12) * CDIM * HWPIX;
    const int hwb  = hw0 + wv * 64 + li;

    const float4* cbsrc = (const float4*)((const unsigned char*)ws + CB_OFF);

    // issue chunk-0 staging loads first (fly under x conversion). 32KB/256thr
    float4 st[8];
#pragma unroll
    for (int i = 0; i < 8; ++i) st[i] = cbsrc[tid + 256 * i];

    e2s[tid]       = ws[tid];
    e2s[tid + 256] = ws[tid + 256];
    if (tid == 0) wlc = 0;

    // ---- x: load + split (-2x) into bf16 hi/lo frags; full ||x||^2 per lane
    float x2p1[4];
    s16x8 xh[4][2], xl[4][2];
#pragma unroll
    for (int g = 0; g < 4; ++g) {
        float vv[16];
#pragma unroll
        for (int ks = 0; ks < 2; ++ks)
#pragma unroll
            for (int i = 0; i < 8; ++i)
                vv[ks * 8 + i] = xb[(ks * 32 + lg * 8 + i) * HWPIX + hwb + g * 16];
        float s = 0.f;
#pragma unroll
        for (int j = 0; j < 16; ++j) s += vv[j] * vv[j];
#pragma unroll
        for (int ks = 0; ks < 2; ++ks) {
            unsigned hws[4], lws[4];
#pragma unroll
            for (int p2 = 0; p2 < 4; ++p2) {
                float m0 = -2.f * vv[ks * 8 + 2 * p2];
                float m1 = -2.f * vv[ks * 8 + 2 * p2 + 1];
                unsigned h = cvt_pk_bf16(m0, m1);
                float h0 = __uint_as_float(h << 16);
                float h1 = __uint_as_float(h & 0xFFFF0000u);
                hws[p2] = h;
                lws[p2] = cvt_pk_bf16(m0 - h0, m1 - h1);
            }
            xh[g][ks] = __builtin_bit_cast(s16x8, (u32x4){hws[0], hws[1], hws[2], hws[3]});
            xl[g][ks] = __builtin_bit_cast(s16x8, (u32x4){lws[0], lws[1], lws[2], lws[3]});
        }
        x2p1[g] = s;
    }
#pragma unroll
    for (int g = 0; g < 4; ++g) {
        x2p1[g] += __shfl_xor(x2p1[g], 16, 64);
        x2p1[g] += __shfl_xor(x2p1[g], 32, 64);
        x2p1[g] += 1.0f;   // dist^2 + 1 > 0 -> monotone u32 keys
    }

    // publish chunk 0
    {
        float4* dst = (float4*)dbuf[0];
#pragma unroll
        for (int i = 0; i < 8; ++i) dst[tid + 256 * i] = st[i];
    }
    __syncthreads();

    unsigned b1[4] = {~0u, ~0u, ~0u, ~0u};
    unsigned b2[4] = {~0u, ~0u, ~0u, ~0u};

    // ---- 4 chunks x 128 codes, LDS double-buffered, register tile pipeline
    for (int c = 0; c < 4; ++c) {
        if (c < 3) {   // issue next-chunk loads; consumed after compute
            const float4* src = cbsrc + (c + 1) * 2048;
#pragma unroll
            for (int i = 0; i < 8; ++i) st[i] = src[tid + 256 * i];
        }
        const unsigned char* bufc = dbuf[c & 1] + lane * 16;
        // prime tile 0 frags
        s16x8 na0 = *(const s16x8*)(bufc);
        s16x8 na1 = *(const s16x8*)(bufc + 1024);
        s16x8 na2 = *(const s16x8*)(bufc + 2048);
        s16x8 na3 = *(const s16x8*)(bufc + 3072);
#pragma unroll
        for (int t = 0; t < 8; ++t) {
            s16x8 ah0 = na0, ah1 = na1, al0 = na2, al1 = na3;
            if (t < 7) {   // prefetch tile t+1 while computing tile t
                const unsigned char* nb = bufc + (t + 1) * 4096;
                na0 = *(const s16x8*)(nb);
                na1 = *(const s16x8*)(nb + 1024);
                na2 = *(const s16x8*)(nb + 2048);
                na3 = *(const s16x8*)(nb + 3072);
            }
            const int kb = c * 128 + t * 16 + lg * 4;
            f32x4 e2v = *(const f32x4*)(e2s + kb);
#pragma unroll
            for (int g = 0; g < 4; ++g) {
                f32x4 acc;
                acc[0] = e2v[0] + x2p1[g];
                acc[1] = e2v[1] + x2p1[g];
                acc[2] = e2v[2] + x2p1[g];
                acc[3] = e2v[3] + x2p1[g];
                acc = __builtin_amdgcn_mfma_f32_16x16x32_bf16(ah0, xh[g][0], acc, 0, 0, 0);
                acc = __builtin_amdgcn_mfma_f32_16x16x32_bf16(ah1, xh[g][1], acc, 0, 0, 0);
                acc = __builtin_amdgcn_mfma_f32_16x16x32_bf16(ah0, xl[g][0], acc, 0, 0, 0);
                acc = __builtin_amdgcn_mfma_f32_16x16x32_bf16(ah1, xl[g][1], acc, 0, 0, 0);
                acc = __builtin_amdgcn_mfma_f32_16x16x32_bf16(al0, xh[g][0], acc, 0, 0, 0);
                acc = __builtin_amdgcn_mfma_f32_16x16x32_bf16(al1, xh[g][1], acc, 0, 0, 0);
                // packed keys: positive dist bits | code; u32 min/max tree
                unsigned K0 = (__float_as_uint(acc[0]) & 0xFFFFFE00u) | (unsigned)(kb + 0);
                unsigned K1 = (__float_as_uint(acc[1]) & 0xFFFFFE00u) | (unsigned)(kb + 1);
                unsigned K2 = (__float_as_uint(acc[2]) & 0xFFFFFE00u) | (unsigned)(kb + 2);
                unsigned K3 = (__float_as_uint(acc[3]) & 0xFFFFFE00u) | (unsigned)(kb + 3);
                unsigned amin = umin_(K0, K1), amax = umax_(K0, K1);
                unsigned bmin = umin_(K2, K3), bmax = umax_(K2, K3);
                unsigned tmin = umin_(amin, bmin);
                unsigned tsnd = umin_(umax_(amin, bmin), umin_(amax, bmax));
                b2[g] = umin_(umin_(b2[g], tsnd), umax_(b1[g], tmin));
                b1[g] = umin_(b1[g], tmin);
            }
        }
        if (c < 3) {   // publish next chunk (other buffer; barrier gates reuse)
            float4* dst = (float4*)dbuf[(c + 1) & 1];
#pragma unroll
            for (int i = 0; i < 8; ++i) dst[tid + 256 * i] = st[i];
        }
        __syncthreads();
    }

    // ---- merge across lane groups; keys give lowest-code tie-break free
#pragma unroll
    for (int g = 0; g < 4; ++g) {
#pragma unroll
        for (int m = 16; m <= 32; m <<= 1) {
            unsigned o1 = (unsigned)__shfl_xor((int)b1[g], m, 64);
            unsigned o2 = (unsigned)__shfl_xor((int)b2[g], m, 64);
            unsigned nb2 = umin_(umin_(b2[g], o2), umax_(b1[g], o1));
            b1[g] = umin_(b1[g], o1);
            b2[g] = nb2;
        }
        if (lane < 16) {
            int p = wv * 64 + g * 16 + lane;
            ls_idx[p]  = (int)(b1[g] & 511u);
            float d1 = __uint_as_float(b1[g] & 0xFFFFFE00u);
            float d2 = __uint_as_float(b2[g] & 0xFFFFFE00u);
            ls_loss[p] = d1 - 1.0f;
            if (d2 - d1 <= TAU) { int w = atomicAdd(&wlc, 1); wl[w] = p; }
        }
    }
    __syncthreads();

    // ---- exact fp64 re-resolution of near-ties (rare, block-cooperative)
    const int nfl = wlc;
    for (int w = 0; w < nfl; ++w) {
        const int p = wl[w];
        const int hwp = hw0 + p;
        double bd = 1e300; int bi = 0;
#pragma unroll
        for (int kk = 0; kk < 2; ++kk) {
            int k = tid * 2 + kk;
            const float* e = emb + k * CDIM;
            double s = 0.0;
            for (int cc = 0; cc < CDIM; ++cc) {
                double t = (double)xb[cc * HWPIX + hwp] - (double)e[cc];
                s += t * t;
            }
            if (s < bd) { bd = s; bi = k; }   // k increasing: lowest wins ties
        }
        // intra-wave reduce (index tie-break -> lowest)
#pragma unroll
        for (int off = 32; off > 0; off >>= 1) {
            double od = __shfl_down(bd, off, 64);
            int    oi = __shfl_down(bi, off, 64);
            if (od < bd || (od == bd && oi < bi)) { bd = od; bi = oi; }
        }
        if (lane == 0) { rbd[wv] = bd; rbi[wv] = bi; }
        __syncthreads();
        if (tid == 0) {
            double BD = rbd[0]; int BI = rbi[0];
#pragma unroll
            for (int i = 1; i < 4; ++i) {
                if (rbd[i] < BD || (rbd[i] == BD && rbi[i] < BI)) { BD = rbd[i]; BI = rbi[i]; }
            }
            ls_idx[p] = BI; ls_loss[p] = (float)BD;
        }
        __syncthreads();
    }

    // ---- outputs
    unsigned* counts = ((unsigned*)ws) + KCODES;
    {
        int k = ls_idx[tid];
        out[2 + n0 + tid] = (float)k;
        atomicAdd(&counts[k], 1u);
    }
    float lv = ls_loss[tid];
#pragma unroll
    for (int off = 32; off > 0; off >>= 1) lv += __shfl_down(lv, off, 64);
    if (lane == 0) wsum[wv] = lv;
    __syncthreads();
    if (tid == 0)
        ws[2 * KCODES + blk] = (wsum[0] + wsum[1]) + (wsum[2] + wsum[3]);
}

__global__ void vq_final(const float* __restrict__ ws, float* __restrict__ out) {
    __shared__ float red[KCODES];
    int t = threadIdx.x;   // 512 threads

    red[t] = ws[2 * KCODES + t];   // 512 block losses
    __syncthreads();
    for (int s = 256; s > 0; s >>= 1) {
        if (t < s) red[t] += red[t + s];
        __syncthreads();
    }
    float loss_sum = red[0];
    __syncthreads();

    unsigned cnt = ((const unsigned*)ws)[KCODES + t];
    float p = (float)cnt / (float)NPIX;
    red[t] = p * logf(p + 1e-10f);
    __syncthreads();
    for (int s = 256; s > 0; s >>= 1) {
        if (t < s) red[t] += red[t + s];
        __syncthreads();
    }
    if (t == 0) {
        out[0] = COMMIT * loss_sum / ((float)NPIX * (float)CDIM);
        out[1] = expf(-red[0]);
    }
}

extern "C" void kernel_launch(void* const* d_in, const int* in_sizes, int n_in,
                              void* d_out, int out_size, void* d_ws, size_t ws_size,
                              hipStream_t stream) {
    const float* in  = (const float*)d_in[0];   // [32, 64, 64, 64] f32
    const float* emb = (const float*)d_in[1];   // [512, 64] f32
    float* out = (float*)d_out;                 // [1 + 1 + 131072] f32
    float* ws  = (float*)d_ws;

    vq_prep<<<2, 256, 0, stream>>>(emb, ws);
    vq_main<<<NBLK, 256, 0, stream>>>(in, emb, ws, out);
    vq_final<<<1, KCODES, 0, stream>>>(ws, out);
}

// Round 11
// 135.172 us; speedup vs baseline: 1.1234x; 1.1234x over previous
//
#include <hip/hip_runtime.h>
#include <math.h>

#define KCODES 512
#define CDIM   64
#define HWPIX  4096
#define NPIX   131072
#define BLKPX  256
#define NBLK   (NPIX / BLKPX)   // 512
#define COMMIT 0.25f
#define TAU    0.03f
#define CB_OFF 8192             // byte offset of codebook frag image in ws

typedef __attribute__((ext_vector_type(8))) short s16x8;   // 8 bf16
typedef __attribute__((ext_vector_type(4))) float f32x4;
typedef __attribute__((ext_vector_type(4))) unsigned u32x4;

static __device__ __forceinline__ unsigned umin_(unsigned a, unsigned b) { return a < b ? a : b; }
static __device__ __forceinline__ unsigned umax_(unsigned a, unsigned b) { return a > b ? a : b; }

static __device__ __forceinline__ unsigned short f2bf(float f) {   // RNE
    unsigned u = __float_as_uint(f);
    u += ((u >> 16) & 1u) + 0x7fffu;
    return (unsigned short)(u >> 16);
}
static __device__ __forceinline__ float bf2f(unsigned short h) {
    return __uint_as_float(((unsigned)h) << 16);
}
static __device__ __forceinline__ unsigned cvt_pk_bf16(float a, float b) {
    unsigned r;   // low half = bf16(a), high half = bf16(b), RNE
    asm("v_cvt_pk_bf16_f32 %0, %1, %2" : "=v"(r) : "v"(a), "v"(b));
    return r;
}

// ws (floats): [0..511] e2 | [512..1023] counts | [1024..1535] blockloss[512]
// byte 8192+: codebook frag image, 32 tiles x 4096B (tile = 16 codes).
// tile: hi frags at ks*1024, lo at 2048+ks*1024; 16B unit (lg*16+row)*16 holds
// code `row`, channels ks*32+lg*8..+7  -> wave A-frag read = base + lane*16.
__global__ void vq_prep(const float* __restrict__ emb, float* __restrict__ ws) {
    int k = blockIdx.x * 256 + threadIdx.x;   // 2 blocks x 256
    const float* e = emb + k * CDIM;
    float v[CDIM];
    double s = 0.0;
#pragma unroll
    for (int c = 0; c < CDIM; ++c) { v[c] = e[c]; s += (double)v[c] * (double)v[c]; }
    ws[k] = (float)s;
    ((unsigned*)ws)[KCODES + k] = 0u;

    unsigned char* base = (unsigned char*)ws + CB_OFF + (k >> 4) * 4096;
    const int row = k & 15;
#pragma unroll
    for (int ks = 0; ks < 2; ++ks) {
#pragma unroll
        for (int lg = 0; lg < 4; ++lg) {
            s16x8 hh, ll;
#pragma unroll
            for (int i = 0; i < 8; ++i) {
                float f = v[ks * 32 + lg * 8 + i];
                unsigned short hb = f2bf(f);
                hh[i] = (short)hb;
                ll[i] = (short)f2bf(f - bf2f(hb));
            }
            int off = (lg * 16 + row) * 16;
            *(s16x8*)(base + ks * 1024 + off)        = hh;
            *(s16x8*)(base + 2048 + ks * 1024 + off) = ll;
        }
    }
}

__global__ __launch_bounds__(256)
void vq_main(const float* __restrict__ in, const float* __restrict__ emb,
             float* __restrict__ ws, float* __restrict__ out) {
    __shared__ __align__(16) unsigned char dbuf[2][32768];   // 128-code chunks
    __shared__ float  e2s[KCODES];
    __shared__ int    ls_idx[BLKPX];
    __shared__ float  ls_loss[BLKPX];
    __shared__ int    wl[BLKPX];
    __shared__ int    wlc;
    __shared__ float  wsum[4];
    __shared__ double rbd[4];
    __shared__ int    rbi[4];

    const int tid  = threadIdx.x;
    const int lane = tid & 63;
    const int wv   = tid >> 6;    // wave id: 64 px each
    const int lg   = lane >> 4;
    const int li   = lane & 15;
    const int blk  = blockIdx.x;
    const int n0   = blk * BLKPX;
    const int hw0  = n0 & 4095;
    const float* xb = in + (size_t)(n0 >> 12) * CDIM * HWPIX;
    const int hwb  = hw0 + wv * 64 + li;

    const float4* cbsrc = (const float4*)((const unsigned char*)ws + CB_OFF);

    // issue chunk-0 staging loads first (fly under x conversion). 32KB/256thr
    float4 st[8];
#pragma unroll
    for (int i = 0; i < 8; ++i) st[i] = cbsrc[tid + 256 * i];

    e2s[tid]       = ws[tid];
    e2s[tid + 256] = ws[tid + 256];
    if (tid == 0) wlc = 0;

    // ---- x: load + split (-2x) into bf16 hi/lo frags; full ||x||^2 per lane
    float x2p1[4];
    s16x8 xh[4][2], xl[4][2];
#pragma unroll
    for (int g = 0; g < 4; ++g) {
        float vv[16];
#pragma unroll
        for (int ks = 0; ks < 2; ++ks)
#pragma unroll
            for (int i = 0; i < 8; ++i)
                vv[ks * 8 + i] = xb[(ks * 32 + lg * 8 + i) * HWPIX + hwb + g * 16];
        float s = 0.f;
#pragma unroll
        for (int j = 0; j < 16; ++j) s += vv[j] * vv[j];
#pragma unroll
        for (int ks = 0; ks < 2; ++ks) {
            unsigned hws[4], lws[4];
#pragma unroll
            for (int p2 = 0; p2 < 4; ++p2) {
                float m0 = -2.f * vv[ks * 8 + 2 * p2];
                float m1 = -2.f * vv[ks * 8 + 2 * p2 + 1];
                unsigned h = cvt_pk_bf16(m0, m1);
                float h0 = __uint_as_float(h << 16);
                float h1 = __uint_as_float(h & 0xFFFF0000u);
                hws[p2] = h;
                lws[p2] = cvt_pk_bf16(m0 - h0, m1 - h1);
            }
            xh[g][ks] = __builtin_bit_cast(s16x8, (u32x4){hws[0], hws[1], hws[2], hws[3]});
            xl[g][ks] = __builtin_bit_cast(s16x8, (u32x4){lws[0], lws[1], lws[2], lws[3]});
        }
        x2p1[g] = s;
    }
#pragma unroll
    for (int g = 0; g < 4; ++g) {
        x2p1[g] += __shfl_xor(x2p1[g], 16, 64);
        x2p1[g] += __shfl_xor(x2p1[g], 32, 64);
        x2p1[g] += 1.0f;   // dist^2 + 1 > 0 -> monotone u32 keys
    }

    // publish chunk 0
    {
        float4* dst = (float4*)dbuf[0];
#pragma unroll
        for (int i = 0; i < 8; ++i) dst[tid + 256 * i] = st[i];
    }
    __syncthreads();

    unsigned b1[4] = {~0u, ~0u, ~0u, ~0u};
    unsigned b2[4] = {~0u, ~0u, ~0u, ~0u};

    // ---- 4 chunks x 128 codes, LDS double-buffered, register tile pipeline
    for (int c = 0; c < 4; ++c) {
        if (c < 3) {   // issue next-chunk loads; consumed after compute
            const float4* src = cbsrc + (c + 1) * 2048;
#pragma unroll
            for (int i = 0; i < 8; ++i) st[i] = src[tid + 256 * i];
        }
        const unsigned char* bufc = dbuf[c & 1] + lane * 16;
        // prime tile 0 frags
        s16x8 na0 = *(const s16x8*)(bufc);
        s16x8 na1 = *(const s16x8*)(bufc + 1024);
        s16x8 na2 = *(const s16x8*)(bufc + 2048);
        s16x8 na3 = *(const s16x8*)(bufc + 3072);
#pragma unroll
        for (int t = 0; t < 8; ++t) {
            s16x8 ah0 = na0, ah1 = na1, al0 = na2, al1 = na3;
            if (t < 7) {   // prefetch tile t+1 while computing tile t
                const unsigned char* nb = bufc + (t + 1) * 4096;
                na0 = *(const s16x8*)(nb);
                na1 = *(const s16x8*)(nb + 1024);
                na2 = *(const s16x8*)(nb + 2048);
                na3 = *(const s16x8*)(nb + 3072);
            }
            const int kb = c * 128 + t * 16 + lg * 4;
            f32x4 e2v = *(const f32x4*)(e2s + kb);
#pragma unroll
            for (int g = 0; g < 4; ++g) {
                f32x4 acc;
                acc[0] = e2v[0] + x2p1[g];
                acc[1] = e2v[1] + x2p1[g];
                acc[2] = e2v[2] + x2p1[g];
                acc[3] = e2v[3] + x2p1[g];
                acc = __builtin_amdgcn_mfma_f32_16x16x32_bf16(ah0, xh[g][0], acc, 0, 0, 0);
                acc = __builtin_amdgcn_mfma_f32_16x16x32_bf16(ah1, xh[g][1], acc, 0, 0, 0);
                acc = __builtin_amdgcn_mfma_f32_16x16x32_bf16(ah0, xl[g][0], acc, 0, 0, 0);
                acc = __builtin_amdgcn_mfma_f32_16x16x32_bf16(ah1, xl[g][1], acc, 0, 0, 0);
                acc = __builtin_amdgcn_mfma_f32_16x16x32_bf16(al0, xh[g][0], acc, 0, 0, 0);
                acc = __builtin_amdgcn_mfma_f32_16x16x32_bf16(al1, xh[g][1], acc, 0, 0, 0);
                // packed keys: positive dist bits | code; u32 min/max tree
                unsigned K0 = (__float_as_uint(acc[0]) & 0xFFFFFE00u) | (unsigned)(kb + 0);
                unsigned K1 = (__float_as_uint(acc[1]) & 0xFFFFFE00u) | (unsigned)(kb + 1);
                unsigned K2 = (__float_as_uint(acc[2]) & 0xFFFFFE00u) | (unsigned)(kb + 2);
                unsigned K3 = (__float_as_uint(acc[3]) & 0xFFFFFE00u) | (unsigned)(kb + 3);
                unsigned amin = umin_(K0, K1), amax = umax_(K0, K1);
                unsigned bmin = umin_(K2, K3), bmax = umax_(K2, K3);
                unsigned tmin = umin_(amin, bmin);
                unsigned tsnd = umin_(umax_(amin, bmin), umin_(amax, bmax));
                b2[g] = umin_(umin_(b2[g], tsnd), umax_(b1[g], tmin));
                b1[g] = umin_(b1[g], tmin);
            }
        }
        if (c < 3) {   // publish next chunk (other buffer; barrier gates reuse)
            float4* dst = (float4*)dbuf[(c + 1) & 1];
#pragma unroll
            for (int i = 0; i < 8; ++i) dst[tid + 256 * i] = st[i];
        }
        __syncthreads();
    }

    // ---- merge across lane groups; keys give lowest-code tie-break free
#pragma unroll
    for (int g = 0; g < 4; ++g) {
#pragma unroll
        for (int m = 16; m <= 32; m <<= 1) {
            unsigned o1 = (unsigned)__shfl_xor((int)b1[g], m, 64);
            unsigned o2 = (unsigned)__shfl_xor((int)b2[g], m, 64);
            unsigned nb2 = umin_(umin_(b2[g], o2), umax_(b1[g], o1));
            b1[g] = umin_(b1[g], o1);
            b2[g] = nb2;
        }
        if (lane < 16) {
            int p = wv * 64 + g * 16 + lane;
            ls_idx[p]  = (int)(b1[g] & 511u);
            float d1 = __uint_as_float(b1[g] & 0xFFFFFE00u);
            float d2 = __uint_as_float(b2[g] & 0xFFFFFE00u);
            ls_loss[p] = d1 - 1.0f;
            if (d2 - d1 <= TAU) { int w = atomicAdd(&wlc, 1); wl[w] = p; }
        }
    }
    __syncthreads();

    // ---- exact fp64 re-resolution of near-ties (rare, block-cooperative)
    const int nfl = wlc;
    for (int w = 0; w < nfl; ++w) {
        const int p = wl[w];
        const int hwp = hw0 + p;
        double bd = 1e300; int bi = 0;
#pragma unroll
        for (int kk = 0; kk < 2; ++kk) {
            int k = tid * 2 + kk;
            const float* e = emb + k * CDIM;
            double s = 0.0;
            for (int cc = 0; cc < CDIM; ++cc) {
                double t = (double)xb[cc * HWPIX + hwp] - (double)e[cc];
                s += t * t;
            }
            if (s < bd) { bd = s; bi = k; }   // k increasing: lowest wins ties
        }
        // intra-wave reduce (index tie-break -> lowest)
#pragma unroll
        for (int off = 32; off > 0; off >>= 1) {
            double od = __shfl_down(bd, off, 64);
            int    oi = __shfl_down(bi, off, 64);
            if (od < bd || (od == bd && oi < bi)) { bd = od; bi = oi; }
        }
        if (lane == 0) { rbd[wv] = bd; rbi[wv] = bi; }
        __syncthreads();
        if (tid == 0) {
            double BD = rbd[0]; int BI = rbi[0];
#pragma unroll
            for (int i = 1; i < 4; ++i) {
                if (rbd[i] < BD || (rbd[i] == BD && rbi[i] < BI)) { BD = rbd[i]; BI = rbi[i]; }
            }
            ls_idx[p] = BI; ls_loss[p] = (float)BD;
        }
        __syncthreads();
    }

    // ---- outputs
    unsigned* counts = ((unsigned*)ws) + KCODES;
    {
        int k = ls_idx[tid];
        out[2 + n0 + tid] = (float)k;
        atomicAdd(&counts[k], 1u);
    }
    float lv = ls_loss[tid];
#pragma unroll
    for (int off = 32; off > 0; off >>= 1) lv += __shfl_down(lv, off, 64);
    if (lane == 0) wsum[wv] = lv;
    __syncthreads();
    if (tid == 0)
        ws[2 * KCODES + blk] = (wsum[0] + wsum[1]) + (wsum[2] + wsum[3]);
}

__global__ void vq_final(const float* __restrict__ ws, float* __restrict__ out) {
    __shared__ float red[KCODES];
    int t = threadIdx.x;   // 512 threads

    red[t] = ws[2 * KCODES + t];   // 512 block losses
    __syncthreads();
    for (int s = 256; s > 0; s >>= 1) {
        if (t < s) red[t] += red[t + s];
        __syncthreads();
    }
    float loss_sum = red[0];
    __syncthreads();

    unsigned cnt = ((const unsigned*)ws)[KCODES + t];
    float p = (float)cnt / (float)NPIX;
    red[t] = p * logf(p + 1e-10f);
    __syncthreads();
    for (int s = 256; s > 0; s >>= 1) {
        if (t < s) red[t] += red[t + s];
        __syncthreads();
    }
    if (t == 0) {
        out[0] = COMMIT * loss_sum / ((float)NPIX * (float)CDIM);
        out[1] = expf(-red[0]);
    }
}

extern "C" void kernel_launch(void* const* d_in, const int* in_sizes, int n_in,
                              void* d_out, int out_size, void* d_ws, size_t ws_size,
                              hipStream_t stream) {
    const float* in  = (const float*)d_in[0];   // [32, 64, 64, 64] f32
    const float* emb = (const float*)d_in[1];   // [512, 64] f32
    float* out = (float*)d_out;                 // [1 + 1 + 131072] f32
    float* ws  = (float*)d_ws;

    vq_prep<<<2, 256, 0, stream>>>(emb, ws);
    vq_main<<<NBLK, 256, 0, stream>>>(in, emb, ws, out);
    vq_final<<<1, KCODES, 0, stream>>>(ws, out);
}

// Round 12
// 112.210 us; speedup vs baseline: 1.3532x; 1.2046x over previous
//
#include <hip/hip_runtime.h>
#include <math.h>

#define KCODES 512
#define CDIM   64
#define HWPIX  4096
#define NPIX   131072
#define BLKPX  128
#define NBLK   (NPIX / BLKPX)   // 1024
#define COMMIT 0.25f
#define TAU    0.03f
#define CB_OFF 8192             // byte offset of codebook frag image in ws

typedef __attribute__((ext_vector_type(8))) short s16x8;   // 8 bf16
typedef __attribute__((ext_vector_type(4))) float f32x4;
typedef __attribute__((ext_vector_type(4))) unsigned u32x4;

static __device__ __forceinline__ unsigned umin_(unsigned a, unsigned b) { return a < b ? a : b; }
static __device__ __forceinline__ unsigned umax_(unsigned a, unsigned b) { return a > b ? a : b; }

static __device__ __forceinline__ unsigned short f2bf(float f) {   // RNE
    unsigned u = __float_as_uint(f);
    u += ((u >> 16) & 1u) + 0x7fffu;
    return (unsigned short)(u >> 16);
}
static __device__ __forceinline__ float bf2f(unsigned short h) {
    return __uint_as_float(((unsigned)h) << 16);
}
static __device__ __forceinline__ unsigned cvt_pk_bf16(float a, float b) {
    unsigned r;   // low half = bf16(a), high half = bf16(b), RNE
    asm("v_cvt_pk_bf16_f32 %0, %1, %2" : "=v"(r) : "v"(a), "v"(b));
    return r;
}

// ws (floats): [0..511] e2 | [512..1023] counts | [1024..2047] blockloss[1024]
// byte 8192+: codebook frag image, 32 tiles x 4096B (tile = 16 codes).
// tile: hi frags at ks*1024, lo at 2048+ks*1024; 16B unit (lg*16+row)*16 holds
// code `row`, channels ks*32+lg*8..+7  -> wave A-frag read = base + lane*16.
__global__ void vq_prep(const float* __restrict__ emb, float* __restrict__ ws) {
    int k = blockIdx.x * 256 + threadIdx.x;   // 2 blocks x 256
    const float* e = emb + k * CDIM;
    float v[CDIM];
    double s = 0.0;
#pragma unroll
    for (int c = 0; c < CDIM; ++c) { v[c] = e[c]; s += (double)v[c] * (double)v[c]; }
    ws[k] = (float)s;
    ((unsigned*)ws)[KCODES + k] = 0u;

    unsigned char* base = (unsigned char*)ws + CB_OFF + (k >> 4) * 4096;
    const int row = k & 15;
#pragma unroll
    for (int ks = 0; ks < 2; ++ks) {
#pragma unroll
        for (int lg = 0; lg < 4; ++lg) {
            s16x8 hh, ll;
#pragma unroll
            for (int i = 0; i < 8; ++i) {
                float f = v[ks * 32 + lg * 8 + i];
                unsigned short hb = f2bf(f);
                hh[i] = (short)hb;
                ll[i] = (short)f2bf(f - bf2f(hb));
            }
            int off = (lg * 16 + row) * 16;
            *(s16x8*)(base + ks * 1024 + off)        = hh;
            *(s16x8*)(base + 2048 + ks * 1024 + off) = ll;
        }
    }
}

__global__ __launch_bounds__(256)
void vq_main(const float* __restrict__ in, const float* __restrict__ emb,
             float* __restrict__ ws, float* __restrict__ out) {
    __shared__ __align__(16) unsigned char dbuf[2][16384];   // 64-code chunks
    __shared__ float  e2s[KCODES];
    __shared__ int    ls_idx[BLKPX];
    __shared__ float  ls_loss[BLKPX];
    __shared__ int    wl[BLKPX];
    __shared__ int    wlc;
    __shared__ float  wsum[4];
    __shared__ double rbd[4];
    __shared__ int    rbi[4];

    const int tid  = threadIdx.x;
    const int lane = tid & 63;
    const int wv   = tid >> 6;    // wave id: 32 px each
    const int lg   = lane >> 4;
    const int li   = lane & 15;
    const int blk  = blockIdx.x;
    const int n0   = blk * BLKPX;
    const int hw0  = n0 & 4095;
    const float* xb = in + (size_t)(n0 >> 12) * CDIM * HWPIX;
    const int hwb  = hw0 + wv * 32 + li;

    const float4* cbsrc = (const float4*)((const unsigned char*)ws + CB_OFF);

    // issue chunk-0 staging loads first (fly under x conversion). 16KB/256thr
    float4 st[4];
#pragma unroll
    for (int i = 0; i < 4; ++i) st[i] = cbsrc[tid + 256 * i];

    e2s[tid]       = ws[tid];
    e2s[tid + 256] = ws[tid + 256];
    if (tid == 0) wlc = 0;

    // ---- x: load + split (-2x) into bf16 hi/lo frags; full ||x||^2 per lane
    float x2p1[2];
    s16x8 xh[2][2], xl[2][2];
#pragma unroll
    for (int g = 0; g < 2; ++g) {
        float vv[16];
#pragma unroll
        for (int ks = 0; ks < 2; ++ks)
#pragma unroll
            for (int i = 0; i < 8; ++i)
                vv[ks * 8 + i] = xb[(ks * 32 + lg * 8 + i) * HWPIX + hwb + g * 16];
        float s = 0.f;
#pragma unroll
        for (int j = 0; j < 16; ++j) s += vv[j] * vv[j];
#pragma unroll
        for (int ks = 0; ks < 2; ++ks) {
            unsigned hws[4], lws[4];
#pragma unroll
            for (int p2 = 0; p2 < 4; ++p2) {
                float m0 = -2.f * vv[ks * 8 + 2 * p2];
                float m1 = -2.f * vv[ks * 8 + 2 * p2 + 1];
                unsigned h = cvt_pk_bf16(m0, m1);
                float h0 = __uint_as_float(h << 16);
                float h1 = __uint_as_float(h & 0xFFFF0000u);
                hws[p2] = h;
                lws[p2] = cvt_pk_bf16(m0 - h0, m1 - h1);
            }
            xh[g][ks] = __builtin_bit_cast(s16x8, (u32x4){hws[0], hws[1], hws[2], hws[3]});
            xl[g][ks] = __builtin_bit_cast(s16x8, (u32x4){lws[0], lws[1], lws[2], lws[3]});
        }
        x2p1[g] = s;
    }
#pragma unroll
    for (int g = 0; g < 2; ++g) {
        x2p1[g] += __shfl_xor(x2p1[g], 16, 64);
        x2p1[g] += __shfl_xor(x2p1[g], 32, 64);
        x2p1[g] += 1.0f;   // dist^2 + 1 > 0 -> monotone u32 keys
    }

    // publish chunk 0
    {
        float4* dst = (float4*)dbuf[0];
#pragma unroll
        for (int i = 0; i < 4; ++i) dst[tid + 256 * i] = st[i];
    }
    __syncthreads();

    unsigned b1[2] = {~0u, ~0u};
    unsigned b2[2] = {~0u, ~0u};

    // ---- 8 chunks x 64 codes, LDS double-buffered, 1 barrier/chunk
    for (int c = 0; c < 8; ++c) {
        if (c < 7) {   // issue next-chunk loads; consumed after compute
            const float4* src = cbsrc + (c + 1) * 1024;
#pragma unroll
            for (int i = 0; i < 4; ++i) st[i] = src[tid + 256 * i];
        }
        const unsigned char* bufc = dbuf[c & 1] + lane * 16;
#pragma unroll
        for (int t = 0; t < 4; ++t) {
            const unsigned char* tb = bufc + t * 4096;
            s16x8 ah0 = *(const s16x8*)(tb);
            s16x8 ah1 = *(const s16x8*)(tb + 1024);
            s16x8 al0 = *(const s16x8*)(tb + 2048);
            s16x8 al1 = *(const s16x8*)(tb + 3072);
            const int kb = c * 64 + t * 16 + lg * 4;
            f32x4 e2v = *(const f32x4*)(e2s + kb);
#pragma unroll
            for (int g = 0; g < 2; ++g) {
                f32x4 acc;
                acc[0] = e2v[0] + x2p1[g];
                acc[1] = e2v[1] + x2p1[g];
                acc[2] = e2v[2] + x2p1[g];
                acc[3] = e2v[3] + x2p1[g];
                acc = __builtin_amdgcn_mfma_f32_16x16x32_bf16(ah0, xh[g][0], acc, 0, 0, 0);
                acc = __builtin_amdgcn_mfma_f32_16x16x32_bf16(ah1, xh[g][1], acc, 0, 0, 0);
                acc = __builtin_amdgcn_mfma_f32_16x16x32_bf16(ah0, xl[g][0], acc, 0, 0, 0);
                acc = __builtin_amdgcn_mfma_f32_16x16x32_bf16(ah1, xl[g][1], acc, 0, 0, 0);
                acc = __builtin_amdgcn_mfma_f32_16x16x32_bf16(al0, xh[g][0], acc, 0, 0, 0);
                acc = __builtin_amdgcn_mfma_f32_16x16x32_bf16(al1, xh[g][1], acc, 0, 0, 0);
                // packed keys: positive dist bits | code; u32 min/max tree
                unsigned K0 = (__float_as_uint(acc[0]) & 0xFFFFFE00u) | (unsigned)(kb + 0);
                unsigned K1 = (__float_as_uint(acc[1]) & 0xFFFFFE00u) | (unsigned)(kb + 1);
                unsigned K2 = (__float_as_uint(acc[2]) & 0xFFFFFE00u) | (unsigned)(kb + 2);
                unsigned K3 = (__float_as_uint(acc[3]) & 0xFFFFFE00u) | (unsigned)(kb + 3);
                unsigned amin = umin_(K0, K1), amax = umax_(K0, K1);
                unsigned bmin = umin_(K2, K3), bmax = umax_(K2, K3);
                unsigned tmin = umin_(amin, bmin);
                unsigned tsnd = umin_(umax_(amin, bmin), umin_(amax, bmax));
                b2[g] = umin_(umin_(b2[g], tsnd), umax_(b1[g], tmin));
                b1[g] = umin_(b1[g], tmin);
            }
        }
        if (c < 7) {   // publish next chunk into the other buffer
            float4* dst = (float4*)dbuf[(c + 1) & 1];
#pragma unroll
            for (int i = 0; i < 4; ++i) dst[tid + 256 * i] = st[i];
        }
        __syncthreads();
    }

    // ---- merge across lane groups; keys give lowest-code tie-break free
#pragma unroll
    for (int g = 0; g < 2; ++g) {
#pragma unroll
        for (int m = 16; m <= 32; m <<= 1) {
            unsigned o1 = (unsigned)__shfl_xor((int)b1[g], m, 64);
            unsigned o2 = (unsigned)__shfl_xor((int)b2[g], m, 64);
            unsigned nb2 = umin_(umin_(b2[g], o2), umax_(b1[g], o1));
            b1[g] = umin_(b1[g], o1);
            b2[g] = nb2;
        }
        if (lane < 16) {
            int p = wv * 32 + g * 16 + lane;
            ls_idx[p]  = (int)(b1[g] & 511u);
            float d1 = __uint_as_float(b1[g] & 0xFFFFFE00u);
            float d2 = __uint_as_float(b2[g] & 0xFFFFFE00u);
            ls_loss[p] = d1 - 1.0f;
            if (d2 - d1 <= TAU) { int w = atomicAdd(&wlc, 1); wl[w] = p; }
        }
    }
    __syncthreads();

    // ---- exact fp64 re-resolution of near-ties (rare, block-cooperative)
    const int nfl = wlc;
    for (int w = 0; w < nfl; ++w) {
        const int p = wl[w];
        const int hwp = hw0 + p;
        double bd = 1e300; int bi = 0;
#pragma unroll
        for (int kk = 0; kk < 2; ++kk) {
            int k = tid * 2 + kk;
            const float* e = emb + k * CDIM;
            double s = 0.0;
        for (int cc = 0; cc < CDIM; ++cc) {
                double t = (double)xb[cc * HWPIX + hwp] - (double)e[cc];
                s += t * t;
            }
            if (s < bd) { bd = s; bi = k; }   // k increasing: lowest wins ties
        }
        // intra-wave reduce (index tie-break -> lowest)
#pragma unroll
        for (int off = 32; off > 0; off >>= 1) {
            double od = __shfl_down(bd, off, 64);
            int    oi = __shfl_down(bi, off, 64);
            if (od < bd || (od == bd && oi < bi)) { bd = od; bi = oi; }
        }
        if (lane == 0) { rbd[wv] = bd; rbi[wv] = bi; }
        __syncthreads();
        if (tid == 0) {
            double BD = rbd[0]; int BI = rbi[0];
#pragma unroll
            for (int i = 1; i < 4; ++i) {
                if (rbd[i] < BD || (rbd[i] == BD && rbi[i] < BI)) { BD = rbd[i]; BI = rbi[i]; }
            }
            ls_idx[p] = BI; ls_loss[p] = (float)BD;
        }
        __syncthreads();
    }

    // ---- outputs
    unsigned* counts = ((unsigned*)ws) + KCODES;
    if (tid < BLKPX) {
        int k = ls_idx[tid];
        out[2 + n0 + tid] = (float)k;
        atomicAdd(&counts[k], 1u);
    }
    float lv = (tid < BLKPX) ? ls_loss[tid] : 0.f;
#pragma unroll
    for (int off = 32; off > 0; off >>= 1) lv += __shfl_down(lv, off, 64);
    if (lane == 0) wsum[wv] = lv;
    __syncthreads();
    if (tid == 0)
        ws[2 * KCODES + blk] = (wsum[0] + wsum[1]) + (wsum[2] + wsum[3]);
}

__global__ void vq_final(const float* __restrict__ ws, float* __restrict__ out) {
    __shared__ float red[KCODES];
    int t = threadIdx.x;   // 512 threads

    red[t] = ws[2 * KCODES + t] + ws[2 * KCODES + 512 + t];   // 1024 block losses
    __syncthreads();
    for (int s = 256; s > 0; s >>= 1) {
        if (t < s) red[t] += red[t + s];
        __syncthreads();
    }
    float loss_sum = red[0];
    __syncthreads();

    unsigned cnt = ((const unsigned*)ws)[KCODES + t];
    float p = (float)cnt / (float)NPIX;
    red[t] = p * logf(p + 1e-10f);
    __syncthreads();
    for (int s = 256; s > 0; s >>= 1) {
        if (t < s) red[t] += red[t + s];
        __syncthreads();
    }
    if (t == 0) {
        out[0] = COMMIT * loss_sum / ((float)NPIX * (float)CDIM);
        out[1] = expf(-red[0]);
    }
}

extern "C" void kernel_launch(void* const* d_in, const int* in_sizes, int n_in,
                              void* d_out, int out_size, void* d_ws, size_t ws_size,
                              hipStream_t stream) {
    const float* in  = (const float*)d_in[0];   // [32, 64, 64, 64] f32
    const float* emb = (const float*)d_in[1];   // [512, 64] f32
    float* out = (float*)d_out;                 // [1 + 1 + 131072] f32
    float* ws  = (float*)d_ws;

    vq_prep<<<2, 256, 0, stream>>>(emb, ws);
    vq_main<<<NBLK, 256, 0, stream>>>(in, emb, ws, out);
    vq_final<<<1, KCODES, 0, stream>>>(ws, out);
}